// Round 6
// baseline (548.357 us; speedup 1.0000x reference)
//
#include <hip/hip_runtime.h>

typedef __bf16 bf16x8 __attribute__((ext_vector_type(8)));
typedef float  f32x4  __attribute__((ext_vector_type(4)));

#define MFMA(a,b,c) __builtin_amdgcn_mfma_f32_16x16x32_bf16((a),(b),(c),0,0,0)
#define SB() __builtin_amdgcn_sched_barrier(0)
#define LGKM0 asm volatile("s_waitcnt lgkmcnt(0)" ::: "memory")

__device__ __forceinline__ unsigned short f2bf(float f){
  unsigned u = __builtin_bit_cast(unsigned, f);
  u += 0x7fffu + ((u>>16)&1u);
  return (unsigned short)(u>>16);
}
__device__ __forceinline__ unsigned pack_bf2(float a, float b){
  return (unsigned)f2bf(a) | ((unsigned)f2bf(b)<<16);
}
__device__ __forceinline__ void gload_lds16(const void* g, void* l){
  __builtin_amdgcn_global_load_lds((__attribute__((address_space(1))) void*)(g),
                                   (__attribute__((address_space(3))) void*)(l), 16, 0, 0);
}

// ---------------- convert x (fp32 -> bf16) ----------------
__global__ void k_cvt_x(const float* __restrict__ x, unsigned short* __restrict__ o){
  const size_t t = (size_t)blockIdx.x*256 + threadIdx.x;
  #pragma unroll
  for (int i=0;i<4;i++){
    size_t idx = t + (size_t)i*1048576;
    float4 f = ((const float4*)x)[idx];
    ((uint2*)o)[idx] = make_uint2(pack_bf2(f.x,f.y), pack_bf2(f.z,f.w));
  }
}

// ---------------- convert + transpose weights: W[K][N] fp32 -> WT[N][K] bf16 ----------------
__global__ void k_cvt_wT(const float* __restrict__ Wq, const float* __restrict__ Wk,
                         const float* __restrict__ Wv, const float* __restrict__ Wo,
                         unsigned short* __restrict__ wT){
  const int z = blockIdx.z;
  const float* W = (z==0)?Wq:(z==1)?Wk:(z==2)?Wv:Wo;
  unsigned short* out = wT + (size_t)z*1048576;
  __shared__ float tile[32][33];
  const int r0 = blockIdx.y*32, c0 = blockIdx.x*32;
  const int r = threadIdx.x>>5, c = threadIdx.x&31;
  #pragma unroll
  for (int i=0;i<4;i++) tile[r + i*8][c] = W[(size_t)(r0 + r + i*8)*1024 + c0 + c];
  __syncthreads();
  #pragma unroll
  for (int i=0;i<4;i++)
    out[(size_t)(c0 + r + i*8)*1024 + r0 + c] = f2bf(tile[c][r + i*8]);
}

// ---------------- 256^2 8-wave pipelined GEMM + ablation variants ----------------
// ABL: 0 = full; 1 = NOSTAGE (no global_load_lds/vmcnt); 2 = NODS (no ds_read/lgkm,
// fabricated frags); 3 = MFMAONLY (barriers + MFMA only).
#define QUAD16(AF, BF, MF0) do { \
  _Pragma("unroll") \
  for (int mf_=0; mf_<4; ++mf_){ \
    _Pragma("unroll") \
    for (int nf_=0; nf_<4; ++nf_) \
      acc[MF0+mf_][nf_] = MFMA(AF[mf_], BF[nf_], acc[MF0+mf_][nf_]); \
  } } while(0)

#define READ_A(DST, MF0, KOFF, AB) do { \
  _Pragma("unroll") \
  for (int mf_=0; mf_<4; ++mf_) \
    DST[mf_] = *(const bf16x8*)((AB) + (((MF0)+mf_)*16+l15)*128 + (((KOFF)+g*16) ^ sw)); \
  } while(0)

#define READ_B(DST, KOFF, BB) do { \
  _Pragma("unroll") \
  for (int nf_=0; nf_<4; ++nf_) \
    DST[nf_] = *(const bf16x8*)((BB) + (brow+nf_*16+l15)*128 + (((KOFF)+g*16) ^ sw)); \
  } while(0)

template<int MODE, int ABL>
__global__ __launch_bounds__(512,2) void k_gemm8(const unsigned short* __restrict__ A,
                       const unsigned short* __restrict__ Bm,
                       const float* __restrict__ bias0, const float* __restrict__ bias1,
                       const float* __restrict__ bias2,
                       unsigned short* __restrict__ q_ws, unsigned short* __restrict__ k_ws,
                       unsigned short* __restrict__ v_ws, float* __restrict__ outf)
{
  constexpr bool DO_STAGE = (ABL==0 || ABL==2);
  constexpr bool DO_DS    = (ABL==0 || ABL==1);

  __shared__ char smem[131072];   // A dbuf 2x32KB @0, B dbuf @65536, XOR-swizzled
  const int tid = threadIdx.x, lane = tid&63, wid = tid>>6;
  const int g = lane>>4, l15 = lane&15;
  const int wr = wid>>2, wc = wid&3;      // 2 x 4 wave grid; wave tile 128x64

  constexpr int NBX = (MODE==0)? 12 : 4;
  constexpr int CPX = (MODE==0)? 96 : 32;
  const int flat = blockIdx.y*NBX + blockIdx.x;
  const int swz  = (flat&7)*CPX + (flat>>3);
  const int m0 = (swz/NBX)<<8, n0 = (swz%NBX)<<8;

  auto stageH = [&](int isA, int tt, int hf){
    char* ldst = smem + (isA?0:65536) + (tt&1)*32768 + hf*16384 + wid*1024;
    const unsigned short* gbase = isA? A : Bm;
    const int row0 = (isA? m0 : n0) + hf*128;
    #pragma unroll
    for (int j=0;j<2;j++){
      const int o = (j*512 + tid)*16;
      const int r = o>>7, cb = o&127;
      const int cs = cb ^ ((r&7)<<4);
      gload_lds16((const char*)gbase + (size_t)(row0 + r)*2048 + (tt<<7) + cs,
                  ldst + j*8192);
    }
  };

  f32x4 acc[8][4];
  #pragma unroll
  for (int i=0;i<8;i++)
    #pragma unroll
    for (int j=0;j<4;j++) acc[i][j] = f32x4{0.f,0.f,0.f,0.f};

  const int sw = (l15&7)<<4;
  const int brow = (wc&1)*64;
  bf16x8 A0f[4], A1f[4], B0f[4], B1f[4];

  // prologue
  if constexpr (DO_STAGE){
    stageH(1,0,0); stageH(1,0,1);
    stageH(0,0,0); stageH(0,0,1);
    stageH(1,1,0); stageH(1,1,1);
    asm volatile("s_waitcnt vmcnt(4)" ::: "memory");
  }
  __builtin_amdgcn_s_barrier();
  SB();
  if constexpr (DO_DS){
    const char* Ab0 = smem + wr*16384;
    const char* Bb0 = smem + 65536 + (wc>>1)*16384;
    READ_A(A0f, 0, 0, Ab0);
    READ_B(B0f, 0, Bb0);
  } else {
    #pragma unroll
    for (int i=0;i<4;i++){
      asm volatile("" : "=v"(A0f[i])); asm volatile("" : "=v"(A1f[i]));
      asm volatile("" : "=v"(B0f[i])); asm volatile("" : "=v"(B1f[i]));
    }
  }

  #pragma unroll 1
  for (int t=0;t<16;++t){
    const char* Abc = smem + (t&1)*32768 + wr*16384;
    const char* Bbc = smem + 65536 + (t&1)*32768 + (wc>>1)*16384;
    const char* Abn = smem + ((t+1)&1)*32768 + wr*16384;
    const char* Bbn = smem + 65536 + ((t+1)&1)*32768 + (wc>>1)*16384;

    // ---------- p0
    if constexpr (DO_DS){ LGKM0; SB(); }
    __builtin_amdgcn_s_barrier(); SB();
    if constexpr (DO_DS) READ_A(A1f, 4, 0, Abc);
    if constexpr (DO_STAGE){ if (t+1 < 16) stageH(0, t+1, 0); }
    SB();
    __builtin_amdgcn_s_setprio(1);
    QUAD16(A0f, B0f, 0);
    __builtin_amdgcn_s_setprio(0);
    SB();

    // ---------- p1
    if constexpr (DO_DS){ LGKM0; SB(); }
    __builtin_amdgcn_s_barrier(); SB();
    if constexpr (DO_DS){ READ_A(A0f, 0, 64, Abc); READ_B(B1f, 64, Bbc); }
    if constexpr (DO_STAGE){ if (t+1 < 16) stageH(0, t+1, 1); }
    SB();
    __builtin_amdgcn_s_setprio(1);
    QUAD16(A1f, B0f, 4);
    __builtin_amdgcn_s_setprio(0);
    SB();

    // ---------- p2
    if constexpr (DO_DS){ LGKM0; SB(); }
    __builtin_amdgcn_s_barrier(); SB();
    if constexpr (DO_DS) READ_A(A1f, 4, 64, Abc);
    SB();
    __builtin_amdgcn_s_setprio(1);
    QUAD16(A0f, B1f, 0);
    __builtin_amdgcn_s_setprio(0);
    SB();

    // ---------- p3
    if constexpr (DO_DS){ LGKM0; SB(); }
    __builtin_amdgcn_s_barrier(); SB();
    if constexpr (DO_STAGE){
      if (t+2 < 16){ stageH(1, t+2, 0); stageH(1, t+2, 1); }
      if (t+1 < 16){
        if (t+2 < 16) asm volatile("s_waitcnt vmcnt(4)" ::: "memory");
        else          asm volatile("s_waitcnt vmcnt(0)" ::: "memory");
      }
    }
    __builtin_amdgcn_s_barrier(); SB();
    if constexpr (DO_DS){
      if (t+1 < 16){
        READ_A(A0f, 0, 0, Abn);
        READ_B(B0f, 0, Bbn);
      }
    }
    SB();
    __builtin_amdgcn_s_setprio(1);
    QUAD16(A1f, B1f, 4);
    __builtin_amdgcn_s_setprio(0);
    SB();
  }

  // ---------------- epilogue ----------------
  if constexpr (MODE==0){
    const int z  = n0>>10;
    const int nE = n0 & 1023;
    const float* bias = (z==0)? bias0 : (z==1)? bias1 : bias2;
    #pragma unroll
    for (int nf=0;nf<4;nf++){
      const int ncol = nE + wc*64 + nf*16 + l15;
      const float bn = bias[ncol];
      const int h = ncol>>6, d = ncol&63;
      #pragma unroll
      for (int mf=0;mf<8;mf++){
        const int mb = m0 + wr*128 + mf*16 + g*4;
        if (z==2){
          const int b = mb>>12, s = mb&4095, nw = s>>8, w0 = s&255;
          unsigned short pk0=f2bf(acc[mf][nf][0]+bn), pk1=f2bf(acc[mf][nf][1]+bn),
                         pk2=f2bf(acc[mf][nf][2]+bn), pk3=f2bf(acc[mf][nf][3]+bn);
          size_t idx = ((((size_t)(b*16+h)*16 + nw)*64 + d)<<8) + w0;
          *(ushort4*)(v_ws + idx) = make_ushort4(pk0,pk1,pk2,pk3);
        } else {
          unsigned short* dst = (z==0)? q_ws : k_ws;
          const float scale = (z==0)? 0.125f : 1.0f;
          #pragma unroll
          for (int r=0;r<4;r++){
            const int m = mb + r, b = m>>12, s = m&4095;
            dst[(((size_t)(b*16+h)*4096 + s)<<6) + d] = f2bf((acc[mf][nf][r]+bn)*scale);
          }
        }
      }
    }
  } else {
    #pragma unroll
    for (int nf=0;nf<4;nf++){
      const int n = n0 + wc*64 + nf*16 + l15;
      const float bn = bias0[n];
      #pragma unroll
      for (int mf=0;mf<8;mf++)
        #pragma unroll
        for (int r=0;r<4;r++){
          const int m = m0 + wr*128 + mf*16 + g*4 + r;
          outf[(size_t)m*1024 + n] = acc[mf][nf][r] + bn;
        }
    }
  }
}

// ---------------- windowed attention: 1 block per (b,h,window), 4 waves x 64 q-rows ----------------
__global__ __launch_bounds__(256,2) void k_attn(const unsigned short* __restrict__ qw,
                                                const unsigned short* __restrict__ kw,
                                                const unsigned short* __restrict__ vw,
                                                unsigned short* __restrict__ ow)
{
  __shared__ unsigned short Ks[2][4096];
  __shared__ unsigned short Vs[2][4096];
  __shared__ unsigned short Ps[4][4096];
  const int tid = threadIdx.x, lane = tid&63, wid = tid>>6;
  const int g = lane>>4, l15 = lane&15;
  const int bhn = blockIdx.x;
  const int nw = bhn&15, h = (bhn>>4)&15, b = bhn>>8;

  const size_t qkbase = ((size_t)((b*16+h)*4096 + nw*256))<<6;
  const unsigned short* Qg = qw + qkbase;
  const unsigned short* Kg = kw + qkbase;
  const unsigned short* Vg = vw + (((size_t)(b*16+h)*16 + nw)<<14);
  const float NEG_INF = -__builtin_inff();

  bf16x8 qa[4][2];
  #pragma unroll
  for (int qf=0;qf<4;qf++)
    #pragma unroll
    for (int ks=0;ks<2;ks++)
      qa[qf][ks] = *(const bf16x8*)((const char*)Qg + (wid*64 + qf*16 + l15)*128 + ks*64 + g*16);

  auto stage = [&](int kt, int bi){
    #pragma unroll
    for (int i=0;i<4;i++){
      const int chunk = wid*4 + i;
      const int obase = (chunk&7)<<10;
      const int o = obase + lane*16;
      const int r = o>>7, cb = o&127;
      const int cs = cb ^ ((r&7)<<4);
      if (chunk < 8)
        gload_lds16((const char*)Kg + (kt*64 + r)*128 + cs, (char*)Ks[bi] + obase);
      else
        gload_lds16((const char*)Vg + r*512 + kt*128 + cs, (char*)Vs[bi] + obase);
    }
  };

  f32x4 oacc[4][4];
  float mrow[4][4], lrow[4][4];
  #pragma unroll
  for (int i=0;i<4;i++)
    #pragma unroll
    for (int j=0;j<4;j++){ oacc[i][j] = f32x4{0.f,0.f,0.f,0.f}; mrow[i][j] = NEG_INF; lrow[i][j] = 0.f; }

  stage(0,0);
  __syncthreads();
  for (int kt=0;kt<4;kt++){
    const int cur = kt&1;
    if (kt<3) stage(kt+1, cur^1);

    bf16x8 kb[4][2];
    #pragma unroll
    for (int kf=0;kf<4;kf++)
      #pragma unroll
      for (int ks=0;ks<2;ks++){
        const int kr = kf*16 + l15, cb = ks*64 + g*16;
        kb[kf][ks] = *(const bf16x8*)((const char*)Ks[cur] + kr*128 + (cb ^ ((kr&7)<<4)));
      }

    unsigned short* P = Ps[wid];
    #pragma unroll
    for (int qf=0;qf<4;qf++){
      f32x4 sfr[4];
      #pragma unroll
      for (int kf=0;kf<4;kf++){
        f32x4 zz = f32x4{0.f,0.f,0.f,0.f};
        zz = MFMA(qa[qf][0], kb[kf][0], zz);
        sfr[kf] = MFMA(qa[qf][1], kb[kf][1], zz);
      }
      #pragma unroll
      for (int r=0;r<4;r++){
        float t = fmaxf(fmaxf(sfr[0][r],sfr[1][r]), fmaxf(sfr[2][r],sfr[3][r]));
        t = fmaxf(t, __shfl_xor(t,1,64)); t = fmaxf(t, __shfl_xor(t,2,64));
        t = fmaxf(t, __shfl_xor(t,4,64)); t = fmaxf(t, __shfl_xor(t,8,64));
        const float mo = mrow[qf][r];
        const float mn = fmaxf(mo, t);
        const float alpha = __expf(mo - mn);
        float rs = 0.f;
        #pragma unroll
        for (int kf=0;kf<4;kf++){ float p = __expf(sfr[kf][r]-mn); sfr[kf][r] = p; rs += p; }
        rs += __shfl_xor(rs,1,64); rs += __shfl_xor(rs,2,64);
        rs += __shfl_xor(rs,4,64); rs += __shfl_xor(rs,8,64);
        lrow[qf][r] = lrow[qf][r]*alpha + rs;
        mrow[qf][r] = mn;
        #pragma unroll
        for (int df=0;df<4;df++) oacc[qf][df][r] *= alpha;
        const int prow = qf*16 + g*4 + r;
        const int sw = (prow&7)<<4;
        char* Pb = (char*)P + prow*128;
        #pragma unroll
        for (int kf=0;kf<4;kf++)
          *(unsigned short*)(Pb + (((kf*16 + l15)*2) ^ sw)) = f2bf(sfr[kf][r]);
      }
    }
    __builtin_amdgcn_sched_barrier(0);

    bf16x8 vb[4][2];
    #pragma unroll
    for (int df=0;df<4;df++)
      #pragma unroll
      for (int ks=0;ks<2;ks++){
        const int d = df*16 + l15, cb = ks*64 + g*16;
        vb[df][ks] = *(const bf16x8*)((const char*)Vs[cur] + d*128 + (cb ^ ((d&7)<<4)));
      }
    #pragma unroll
    for (int qf=0;qf<4;qf++){
      const int pr = qf*16 + l15;
      const bf16x8 pa0 = *(const bf16x8*)((const char*)P + pr*128 + ((g*16)      ^ ((pr&7)<<4)));
      const bf16x8 pa1 = *(const bf16x8*)((const char*)P + pr*128 + ((64 + g*16) ^ ((pr&7)<<4)));
      #pragma unroll
      for (int df=0;df<4;df++){
        oacc[qf][df] = MFMA(pa0, vb[df][0], oacc[qf][df]);
        oacc[qf][df] = MFMA(pa1, vb[df][1], oacc[qf][df]);
      }
    }
    __syncthreads();
  }

  #pragma unroll
  for (int qf=0;qf<4;qf++)
    #pragma unroll
    for (int r=0;r<4;r++){
      const float inv = 1.f / lrow[qf][r];
      const int srow = nw*256 + wid*64 + qf*16 + g*4 + r;
      const size_t base = ((size_t)b*4096 + srow)*1024 + (size_t)h*64;
      #pragma unroll
      for (int df=0;df<4;df++)
        ow[base + df*16 + l15] = f2bf(oacc[qf][df][r]*inv);
    }
}

// ---------------- launch ----------------
extern "C" void kernel_launch(void* const* d_in, const int* in_sizes, int n_in,
                              void* d_out, int out_size, void* d_ws, size_t ws_size,
                              hipStream_t stream)
{
  const float* x  = (const float*)d_in[0];
  const float* Wq = (const float*)d_in[1];
  const float* bq = (const float*)d_in[2];
  const float* Wk = (const float*)d_in[3];
  const float* bk = (const float*)d_in[4];
  const float* Wv = (const float*)d_in[5];
  const float* bv = (const float*)d_in[6];
  const float* Wo = (const float*)d_in[7];
  const float* bo = (const float*)d_in[8];
  float* out = (float*)d_out;

  char* ws = (char*)d_ws;
  unsigned short* xbf  = (unsigned short*)(ws);
  unsigned short* wT   = (unsigned short*)(ws + (size_t)32*1048576);
  unsigned short* q_ws = (unsigned short*)(ws + (size_t)40*1048576);
  unsigned short* k_ws = (unsigned short*)(ws + (size_t)72*1048576);
  unsigned short* v_ws = (unsigned short*)(ws + (size_t)104*1048576);
  unsigned short* obf  = xbf;

  k_cvt_x<<<4096,256,0,stream>>>(x, xbf);
  k_cvt_wT<<<dim3(32,32,4),256,0,stream>>>(Wq,Wk,Wv,Wo, wT);

  // --- ablation probes (write garbage into q/k/v_ws; overwritten by the real V0 below) ---
  k_gemm8<0,1><<<dim3(12,64),512,0,stream>>>(xbf, wT, bq,bk,bv, q_ws,k_ws,v_ws, nullptr); // V1 NOSTAGE
  k_gemm8<0,2><<<dim3(12,64),512,0,stream>>>(xbf, wT, bq,bk,bv, q_ws,k_ws,v_ws, nullptr); // V2 NODS
  k_gemm8<0,3><<<dim3(12,64),512,0,stream>>>(xbf, wT, bq,bk,bv, q_ws,k_ws,v_ws, nullptr); // V3 MFMAONLY

  // --- real pipeline ---
  k_gemm8<0,0><<<dim3(12,64),512,0,stream>>>(xbf, wT, bq,bk,bv, q_ws,k_ws,v_ws, nullptr);
  k_attn<<<1024,256,0,stream>>>(q_ws,k_ws,v_ws, obf);
  k_gemm8<1,0><<<dim3(4,64),512,0,stream>>>(obf, wT + (size_t)3*1048576, bo,nullptr,nullptr,
                                            nullptr,nullptr,nullptr, out);
}

// Round 7
// 260.619 us; speedup vs baseline: 2.1041x; 2.1041x over previous
//
#include <hip/hip_runtime.h>

typedef __bf16 bf16x8 __attribute__((ext_vector_type(8)));
typedef float  f32x4  __attribute__((ext_vector_type(4)));

#define MFMA(a,b,c) __builtin_amdgcn_mfma_f32_16x16x32_bf16((a),(b),(c),0,0,0)
#define SB() __builtin_amdgcn_sched_barrier(0)
#define LGKM0 asm volatile("s_waitcnt lgkmcnt(0)" ::: "memory")
#define VMC(N) asm volatile("s_waitcnt vmcnt(" #N ")" ::: "memory")

__device__ __forceinline__ unsigned short f2bf(float f){
  unsigned u = __builtin_bit_cast(unsigned, f);
  u += 0x7fffu + ((u>>16)&1u);
  return (unsigned short)(u>>16);
}
__device__ __forceinline__ unsigned pack_bf2(float a, float b){
  return (unsigned)f2bf(a) | ((unsigned)f2bf(b)<<16);
}
__device__ __forceinline__ void gload_lds16(const void* g, void* l){
  __builtin_amdgcn_global_load_lds((__attribute__((address_space(1))) void*)(g),
                                   (__attribute__((address_space(3))) void*)(l), 16, 0, 0);
}

// ---------------- convert x (fp32 -> bf16) ----------------
__global__ void k_cvt_x(const float* __restrict__ x, unsigned short* __restrict__ o){
  const size_t t = (size_t)blockIdx.x*256 + threadIdx.x;
  #pragma unroll
  for (int i=0;i<4;i++){
    size_t idx = t + (size_t)i*1048576;
    float4 f = ((const float4*)x)[idx];
    ((uint2*)o)[idx] = make_uint2(pack_bf2(f.x,f.y), pack_bf2(f.z,f.w));
  }
}

// ---------------- convert + transpose weights: W[K][N] fp32 -> WT[N][K] bf16 ----------------
__global__ void k_cvt_wT(const float* __restrict__ Wq, const float* __restrict__ Wk,
                         const float* __restrict__ Wv, const float* __restrict__ Wo,
                         unsigned short* __restrict__ wT){
  const int z = blockIdx.z;
  const float* W = (z==0)?Wq:(z==1)?Wk:(z==2)?Wv:Wo;
  unsigned short* out = wT + (size_t)z*1048576;
  __shared__ float tile[32][33];
  const int r0 = blockIdx.y*32, c0 = blockIdx.x*32;
  const int r = threadIdx.x>>5, c = threadIdx.x&31;
  #pragma unroll
  for (int i=0;i<4;i++) tile[r + i*8][c] = W[(size_t)(r0 + r + i*8)*1024 + c0 + c];
  __syncthreads();
  #pragma unroll
  for (int i=0;i<4;i++)
    out[(size_t)(c0 + r + i*8)*1024 + r0 + c] = f2bf(tile[c][r + i*8]);
}

// ---------------- 256^2 8-wave 8-phase GEMM (m201-faithful) ----------------
// Phase: {reads(4|8) ; stage 1 half-tile ; barrier ; lgkm0 ; 16 MFMA ; [vmcnt@ph4/8] ; barrier}
// Stage slots per iter (tiles T,T+1): ph1 B1(T+1), ph2 A0(T+1), ph3 A1(T+1), ph4 B0(T+2)+vmcnt(2),
// ph5 B1(T+2), ph6 A0(T+2), ph7 A1(T+2), ph8 B0(T+3)+vmcnt(2).
#define QUAD16(AF, BF, MF0) do { \
  _Pragma("unroll") \
  for (int mf_=0; mf_<4; ++mf_){ \
    _Pragma("unroll") \
    for (int nf_=0; nf_<4; ++nf_) \
      acc[MF0+mf_][nf_] = MFMA(AF[mf_], BF[nf_], acc[MF0+mf_][nf_]); \
  } } while(0)

#define READ_A(DST, MF0, KOFF, AB) do { \
  _Pragma("unroll") \
  for (int mf_=0; mf_<4; ++mf_) \
    DST[mf_] = *(const bf16x8*)((AB) + (((MF0)+mf_)*16+l15)*128 + (((KOFF)+g*16) ^ sw)); \
  } while(0)

#define READ_B(DST, KOFF, BB) do { \
  _Pragma("unroll") \
  for (int nf_=0; nf_<4; ++nf_) \
    DST[nf_] = *(const bf16x8*)((BB) + (brow+nf_*16+l15)*128 + (((KOFF)+g*16) ^ sw)); \
  } while(0)

#define PH_OPEN   SB(); __builtin_amdgcn_s_barrier(); LGKM0; SB(); __builtin_amdgcn_s_setprio(1)
#define PH_CLOSE  __builtin_amdgcn_s_setprio(0); SB()
#define PH_END    __builtin_amdgcn_s_barrier(); SB()

template<int MODE>
__global__ __launch_bounds__(512,2) void k_gemm8(const unsigned short* __restrict__ A,
                       const unsigned short* __restrict__ Bm,
                       const float* __restrict__ bias0, const float* __restrict__ bias1,
                       const float* __restrict__ bias2,
                       unsigned short* __restrict__ q_ws, unsigned short* __restrict__ k_ws,
                       unsigned short* __restrict__ v_ws, float* __restrict__ outf)
{
  __shared__ char smem[131072];   // A: par*32768+half*16384 @0 ; B same @65536 ; XOR-swizzled
  const int tid = threadIdx.x, lane = tid&63, wid = tid>>6;
  const int g = lane>>4, l15 = lane&15;
  const int wr = wid>>2, wc = wid&3;      // 2M x 4N wave grid; wave tile 128x64

  // n-fastest, XCD-aligned m-bands: XCD x owns m-blocks {8k+x} (A L2-resident, B streams)
  constexpr int NN = (MODE==0)? 12 : 4;
  const int x  = blockIdx.x & 7;
  const int c  = blockIdx.x >> 3;
  const int m0 = ((c/NN)*8 + x) << 8;
  const int n0 = (c%NN) << 8;

  auto stageH = [&](int isA, int tt, int hf){
    char* ldst = smem + (isA?0:65536) + (tt&1)*32768 + hf*16384 + wid*1024;
    const unsigned short* gbase = isA? A : Bm;
    const int row0 = (isA? m0 : n0) + hf*128;
    #pragma unroll
    for (int j=0;j<2;j++){
      const int o = (j*512 + tid)*16;
      const int r = o>>7, cb = o&127;
      const int cs = cb ^ ((r&7)<<4);
      gload_lds16((const char*)gbase + (size_t)(row0 + r)*2048 + (tt<<7) + cs,
                  ldst + j*8192);
    }
  };

  f32x4 acc[8][4];
  #pragma unroll
  for (int i=0;i<8;i++)
    #pragma unroll
    for (int j=0;j<4;j++) acc[i][j] = f32x4{0.f,0.f,0.f,0.f};

  const int sw = (l15&7)<<4;
  const int brow = (wc&1)*64;
  const char* Ab0 = smem + wr*16384;
  const char* Bb0 = smem + 65536 + (wc>>1)*16384;
  const char* Ab1 = Ab0 + 32768;
  const char* Bb1 = Bb0 + 32768;
  bf16x8 aF[4], bF[4];

  // prologue: tile0 fully + B0(1); vmcnt(2) leaves B0(1) in flight
  stageH(1,0,0); stageH(1,0,1); stageH(0,0,0); stageH(0,0,1);
  stageH(0,1,0);
  VMC(2);
  __builtin_amdgcn_s_barrier(); SB();

  #pragma unroll 1
  for (int i=0;i<7;++i){
    const int T = 2*i;
    // ph1: A[ks0,mf0-3](T) + B[ks0](T); stage B1(T+1); MFMA(0,ks0)
    READ_A(aF,0,0,Ab0); READ_B(bF,0,Bb0); stageH(0,T+1,1);
    PH_OPEN; QUAD16(aF,bF,0); PH_CLOSE; PH_END;
    // ph2: A[ks0,mf4-7](T); stage A0(T+1); MFMA(4,ks0)
    READ_A(aF,4,0,Ab0); stageH(1,T+1,0);
    PH_OPEN; QUAD16(aF,bF,4); PH_CLOSE; PH_END;
    // ph3: A[ks1,mf0-3](T) + B[ks1](T); stage A1(T+1); MFMA(0,ks1)
    READ_A(aF,0,64,Ab0); READ_B(bF,64,Bb0); stageH(1,T+1,1);
    PH_OPEN; QUAD16(aF,bF,0); PH_CLOSE; PH_END;
    // ph4: A[ks1,mf4-7](T); stage B0(T+2); MFMA(4,ks1); vmcnt(2) -> tile T+1 landed
    READ_A(aF,4,64,Ab0); stageH(0,T+2,0);
    PH_OPEN; QUAD16(aF,bF,4); PH_CLOSE; VMC(2); PH_END;
    // ph5: tile T+1 ks0 mf0-3 + B; stage B1(T+2); MFMA(0,ks0)
    READ_A(aF,0,0,Ab1); READ_B(bF,0,Bb1); stageH(0,T+2,1);
    PH_OPEN; QUAD16(aF,bF,0); PH_CLOSE; PH_END;
    // ph6: stage A0(T+2)
    READ_A(aF,4,0,Ab1); stageH(1,T+2,0);
    PH_OPEN; QUAD16(aF,bF,4); PH_CLOSE; PH_END;
    // ph7: stage A1(T+2)
    READ_A(aF,0,64,Ab1); READ_B(bF,64,Bb1); stageH(1,T+2,1);
    PH_OPEN; QUAD16(aF,bF,0); PH_CLOSE; PH_END;
    // ph8: stage B0(T+3); vmcnt(2) -> tile T+2 landed
    READ_A(aF,4,64,Ab1); stageH(0,T+3,0);
    PH_OPEN; QUAD16(aF,bF,4); PH_CLOSE; VMC(2); PH_END;
  }
  {
    // tail: tiles 14,15 — finish staging tile15 (B1,A0,A1), no further prefetch
    READ_A(aF,0,0,Ab0); READ_B(bF,0,Bb0); stageH(0,15,1);
    PH_OPEN; QUAD16(aF,bF,0); PH_CLOSE; PH_END;
    READ_A(aF,4,0,Ab0); stageH(1,15,0);
    PH_OPEN; QUAD16(aF,bF,4); PH_CLOSE; PH_END;
    READ_A(aF,0,64,Ab0); READ_B(bF,64,Bb0); stageH(1,15,1);
    PH_OPEN; QUAD16(aF,bF,0); PH_CLOSE; PH_END;
    READ_A(aF,4,64,Ab0);
    PH_OPEN; QUAD16(aF,bF,4); PH_CLOSE; VMC(0); PH_END;
    READ_A(aF,0,0,Ab1); READ_B(bF,0,Bb1);
    PH_OPEN; QUAD16(aF,bF,0); PH_CLOSE; PH_END;
    READ_A(aF,4,0,Ab1);
    PH_OPEN; QUAD16(aF,bF,4); PH_CLOSE; PH_END;
    READ_A(aF,0,64,Ab1); READ_B(bF,64,Bb1);
    PH_OPEN; QUAD16(aF,bF,0); PH_CLOSE; PH_END;
    READ_A(aF,4,64,Ab1);
    PH_OPEN; QUAD16(aF,bF,4); PH_CLOSE; PH_END;
  }

  // ---------------- epilogue ----------------
  if constexpr (MODE==0){
    const int z  = n0>>10;
    const int nE = n0 & 1023;
    const float* bias = (z==0)? bias0 : (z==1)? bias1 : bias2;
    #pragma unroll
    for (int nf=0;nf<4;nf++){
      const int ncol = nE + wc*64 + nf*16 + l15;
      const float bn = bias[ncol];
      const int h = ncol>>6, d = ncol&63;
      #pragma unroll
      for (int mf=0;mf<8;mf++){
        const int mb = m0 + wr*128 + mf*16 + g*4;
        if (z==2){
          const int b = mb>>12, s = mb&4095, nw = s>>8, w0 = s&255;
          unsigned short pk0=f2bf(acc[mf][nf][0]+bn), pk1=f2bf(acc[mf][nf][1]+bn),
                         pk2=f2bf(acc[mf][nf][2]+bn), pk3=f2bf(acc[mf][nf][3]+bn);
          size_t idx = ((((size_t)(b*16+h)*16 + nw)*64 + d)<<8) + w0;
          *(ushort4*)(v_ws + idx) = make_ushort4(pk0,pk1,pk2,pk3);
        } else {
          unsigned short* dst = (z==0)? q_ws : k_ws;
          const float scale = (z==0)? 0.125f : 1.0f;
          #pragma unroll
          for (int r=0;r<4;r++){
            const int m = mb + r, b = m>>12, s = m&4095;
            dst[(((size_t)(b*16+h)*4096 + s)<<6) + d] = f2bf((acc[mf][nf][r]+bn)*scale);
          }
        }
      }
    }
  } else {
    #pragma unroll
    for (int nf=0;nf<4;nf++){
      const int n = n0 + wc*64 + nf*16 + l15;
      const float bn = bias0[n];
      #pragma unroll
      for (int mf=0;mf<8;mf++)
        #pragma unroll
        for (int r=0;r<4;r++){
          const int m = m0 + wr*128 + mf*16 + g*4 + r;
          outf[(size_t)m*1024 + n] = acc[mf][nf][r] + bn;
        }
    }
  }
}

// ---------------- windowed attention: 1 block per (b,h,window), 4 waves x 64 q-rows ----------------
__global__ __launch_bounds__(256,2) void k_attn(const unsigned short* __restrict__ qw,
                                                const unsigned short* __restrict__ kw,
                                                const unsigned short* __restrict__ vw,
                                                unsigned short* __restrict__ ow)
{
  __shared__ unsigned short Ks[2][4096];
  __shared__ unsigned short Vs[2][4096];
  __shared__ unsigned short Ps[4][4096];
  const int tid = threadIdx.x, lane = tid&63, wid = tid>>6;
  const int g = lane>>4, l15 = lane&15;
  const int bhn = blockIdx.x;
  const int nw = bhn&15, h = (bhn>>4)&15, b = bhn>>8;

  const size_t qkbase = ((size_t)((b*16+h)*4096 + nw*256))<<6;
  const unsigned short* Qg = qw + qkbase;
  const unsigned short* Kg = kw + qkbase;
  const unsigned short* Vg = vw + (((size_t)(b*16+h)*16 + nw)<<14);
  const float NEG_INF = -__builtin_inff();

  bf16x8 qa[4][2];
  #pragma unroll
  for (int qf=0;qf<4;qf++)
    #pragma unroll
    for (int ks=0;ks<2;ks++)
      qa[qf][ks] = *(const bf16x8*)((const char*)Qg + (wid*64 + qf*16 + l15)*128 + ks*64 + g*16);

  auto stage = [&](int kt, int bi){
    #pragma unroll
    for (int i=0;i<4;i++){
      const int chunk = wid*4 + i;
      const int obase = (chunk&7)<<10;
      const int o = obase + lane*16;
      const int r = o>>7, cb = o&127;
      const int cs = cb ^ ((r&7)<<4);
      if (chunk < 8)
        gload_lds16((const char*)Kg + (kt*64 + r)*128 + cs, (char*)Ks[bi] + obase);
      else
        gload_lds16((const char*)Vg + r*512 + kt*128 + cs, (char*)Vs[bi] + obase);
    }
  };

  f32x4 oacc[4][4];
  float mrow[4][4], lrow[4][4];
  #pragma unroll
  for (int i=0;i<4;i++)
    #pragma unroll
    for (int j=0;j<4;j++){ oacc[i][j] = f32x4{0.f,0.f,0.f,0.f}; mrow[i][j] = NEG_INF; lrow[i][j] = 0.f; }

  stage(0,0);
  __syncthreads();
  for (int kt=0;kt<4;kt++){
    const int cur = kt&1;
    if (kt<3) stage(kt+1, cur^1);

    bf16x8 kb[4][2];
    #pragma unroll
    for (int kf=0;kf<4;kf++)
      #pragma unroll
      for (int ks=0;ks<2;ks++){
        const int kr = kf*16 + l15, cb = ks*64 + g*16;
        kb[kf][ks] = *(const bf16x8*)((const char*)Ks[cur] + kr*128 + (cb ^ ((kr&7)<<4)));
      }

    unsigned short* P = Ps[wid];
    #pragma unroll
    for (int qf=0;qf<4;qf++){
      f32x4 sfr[4];
      #pragma unroll
      for (int kf=0;kf<4;kf++){
        f32x4 zz = f32x4{0.f,0.f,0.f,0.f};
        zz = MFMA(qa[qf][0], kb[kf][0], zz);
        sfr[kf] = MFMA(qa[qf][1], kb[kf][1], zz);
      }
      #pragma unroll
      for (int r=0;r<4;r++){
        float t = fmaxf(fmaxf(sfr[0][r],sfr[1][r]), fmaxf(sfr[2][r],sfr[3][r]));
        t = fmaxf(t, __shfl_xor(t,1,64)); t = fmaxf(t, __shfl_xor(t,2,64));
        t = fmaxf(t, __shfl_xor(t,4,64)); t = fmaxf(t, __shfl_xor(t,8,64));
        const float mo = mrow[qf][r];
        const float mn = fmaxf(mo, t);
        const float alpha = __expf(mo - mn);
        float rs = 0.f;
        #pragma unroll
        for (int kf=0;kf<4;kf++){ float p = __expf(sfr[kf][r]-mn); sfr[kf][r] = p; rs += p; }
        rs += __shfl_xor(rs,1,64); rs += __shfl_xor(rs,2,64);
        rs += __shfl_xor(rs,4,64); rs += __shfl_xor(rs,8,64);
        lrow[qf][r] = lrow[qf][r]*alpha + rs;
        mrow[qf][r] = mn;
        #pragma unroll
        for (int df=0;df<4;df++) oacc[qf][df][r] *= alpha;
        const int prow = qf*16 + g*4 + r;
        const int sw = (prow&7)<<4;
        char* Pb = (char*)P + prow*128;
        #pragma unroll
        for (int kf=0;kf<4;kf++)
          *(unsigned short*)(Pb + (((kf*16 + l15)*2) ^ sw)) = f2bf(sfr[kf][r]);
      }
    }
    __builtin_amdgcn_sched_barrier(0);

    bf16x8 vb[4][2];
    #pragma unroll
    for (int df=0;df<4;df++)
      #pragma unroll
      for (int ks=0;ks<2;ks++){
        const int d = df*16 + l15, cb = ks*64 + g*16;
        vb[df][ks] = *(const bf16x8*)((const char*)Vs[cur] + d*128 + (cb ^ ((d&7)<<4)));
      }
    #pragma unroll
    for (int qf=0;qf<4;qf++){
      const int pr = qf*16 + l15;
      const bf16x8 pa0 = *(const bf16x8*)((const char*)P + pr*128 + ((g*16)      ^ ((pr&7)<<4)));
      const bf16x8 pa1 = *(const bf16x8*)((const char*)P + pr*128 + ((64 + g*16) ^ ((pr&7)<<4)));
      #pragma unroll
      for (int df=0;df<4;df++){
        oacc[qf][df] = MFMA(pa0, vb[df][0], oacc[qf][df]);
        oacc[qf][df] = MFMA(pa1, vb[df][1], oacc[qf][df]);
      }
    }
    __syncthreads();
  }

  #pragma unroll
  for (int qf=0;qf<4;qf++)
    #pragma unroll
    for (int r=0;r<4;r++){
      const float inv = 1.f / lrow[qf][r];
      const int srow = nw*256 + wid*64 + qf*16 + g*4 + r;
      const size_t base = ((size_t)b*4096 + srow)*1024 + (size_t)h*64;
      #pragma unroll
      for (int df=0;df<4;df++)
        ow[base + df*16 + l15] = f2bf(oacc[qf][df][r]*inv);
    }
}

// ---------------- launch ----------------
extern "C" void kernel_launch(void* const* d_in, const int* in_sizes, int n_in,
                              void* d_out, int out_size, void* d_ws, size_t ws_size,
                              hipStream_t stream)
{
  const float* x  = (const float*)d_in[0];
  const float* Wq = (const float*)d_in[1];
  const float* bq = (const float*)d_in[2];
  const float* Wk = (const float*)d_in[3];
  const float* bk = (const float*)d_in[4];
  const float* Wv = (const float*)d_in[5];
  const float* bv = (const float*)d_in[6];
  const float* Wo = (const float*)d_in[7];
  const float* bo = (const float*)d_in[8];
  float* out = (float*)d_out;

  char* ws = (char*)d_ws;
  unsigned short* xbf  = (unsigned short*)(ws);
  unsigned short* wT   = (unsigned short*)(ws + (size_t)32*1048576);
  unsigned short* q_ws = (unsigned short*)(ws + (size_t)40*1048576);
  unsigned short* k_ws = (unsigned short*)(ws + (size_t)72*1048576);
  unsigned short* v_ws = (unsigned short*)(ws + (size_t)104*1048576);
  unsigned short* obf  = xbf;

  k_cvt_x<<<4096,256,0,stream>>>(x, xbf);
  k_cvt_wT<<<dim3(32,32,4),256,0,stream>>>(Wq,Wk,Wv,Wo, wT);
  k_gemm8<0><<<768,512,0,stream>>>(xbf, wT, bq,bk,bv, q_ws,k_ws,v_ws, nullptr);
  k_attn<<<1024,256,0,stream>>>(q_ws,k_ws,v_ws, obf);
  k_gemm8<1><<<256,512,0,stream>>>(obf, wT + (size_t)3*1048576, bo,nullptr,nullptr,
                                   nullptr,nullptr,nullptr, out);
}

// Round 8
// 256.241 us; speedup vs baseline: 2.1400x; 1.0171x over previous
//
#include <hip/hip_runtime.h>

typedef __bf16 bf16x8 __attribute__((ext_vector_type(8)));
typedef float  f32x4  __attribute__((ext_vector_type(4)));

#define MFMA(a,b,c) __builtin_amdgcn_mfma_f32_16x16x32_bf16((a),(b),(c),0,0,0)
#define SB() __builtin_amdgcn_sched_barrier(0)
#define LGKM0 asm volatile("s_waitcnt lgkmcnt(0)" ::: "memory")
#define VMC(N) asm volatile("s_waitcnt vmcnt(" #N ")" ::: "memory")

__device__ __forceinline__ unsigned short f2bf(float f){
  unsigned u = __builtin_bit_cast(unsigned, f);
  u += 0x7fffu + ((u>>16)&1u);
  return (unsigned short)(u>>16);
}
__device__ __forceinline__ unsigned pack_bf2(float a, float b){
  return (unsigned)f2bf(a) | ((unsigned)f2bf(b)<<16);
}
__device__ __forceinline__ void gload_lds16(const void* g, void* l){
  __builtin_amdgcn_global_load_lds((__attribute__((address_space(1))) void*)(g),
                                   (__attribute__((address_space(3))) void*)(l), 16, 0, 0);
}

// ---------------- convert x (fp32 -> bf16) ----------------
__global__ void k_cvt_x(const float* __restrict__ x, unsigned short* __restrict__ o){
  const size_t t = (size_t)blockIdx.x*256 + threadIdx.x;
  #pragma unroll
  for (int i=0;i<4;i++){
    size_t idx = t + (size_t)i*1048576;
    float4 f = ((const float4*)x)[idx];
    ((uint2*)o)[idx] = make_uint2(pack_bf2(f.x,f.y), pack_bf2(f.z,f.w));
  }
}

// ---------------- convert + transpose weights: W[K][N] fp32 -> WT[N][K] bf16 ----------------
__global__ void k_cvt_wT(const float* __restrict__ Wq, const float* __restrict__ Wk,
                         const float* __restrict__ Wv, const float* __restrict__ Wo,
                         unsigned short* __restrict__ wT){
  const int z = blockIdx.z;
  const float* W = (z==0)?Wq:(z==1)?Wk:(z==2)?Wv:Wo;
  unsigned short* out = wT + (size_t)z*1048576;
  __shared__ float tile[32][33];
  const int r0 = blockIdx.y*32, c0 = blockIdx.x*32;
  const int r = threadIdx.x>>5, c = threadIdx.x&31;
  #pragma unroll
  for (int i=0;i<4;i++) tile[r + i*8][c] = W[(size_t)(r0 + r + i*8)*1024 + c0 + c];
  __syncthreads();
  #pragma unroll
  for (int i=0;i<4;i++)
    out[(size_t)(c0 + r + i*8)*1024 + r0 + c] = f2bf(tile[c][r + i*8]);
}

// ---------------- 256^2 8-wave 8-phase GEMM, hoisted base+imm addressing ----------------
// Skeleton identical to r7; ALL ds_read / stage addresses are loop-invariant base pointers
// + compile-time immediates (no per-phase VALU address recompute).
#define QUAD16(AF, BF, MF0) do { \
  _Pragma("unroll") \
  for (int mf_=0; mf_<4; ++mf_){ \
    _Pragma("unroll") \
    for (int nf_=0; nf_<4; ++nf_) \
      acc[MF0+mf_][nf_] = MFMA(AF[mf_], BF[nf_], acc[MF0+mf_][nf_]); \
  } } while(0)

#define RDA(DST, MF0, P) do { \
  _Pragma("unroll") \
  for (int mf_=0; mf_<4; ++mf_) \
    DST[mf_] = *(const bf16x8*)((P) + ((MF0)+mf_)*2048); \
  } while(0)

#define RDB(DST, P) do { \
  _Pragma("unroll") \
  for (int nf_=0; nf_<4; ++nf_) \
    DST[nf_] = *(const bf16x8*)((P) + nf_*2048); \
  } while(0)

// stage one 16KB half-tile: 2 gload_lds from precomputed per-lane ptrs + imm delta
#define STG2(P0, P1, DT, ISA, BUF, HF) do { \
  char* _ld = smem + ((ISA)?0:65536) + (BUF)*32768 + (HF)*16384 + wid*1024; \
  gload_lds16((P0) + (DT), _ld); \
  gload_lds16((P1) + (DT), _ld + 8192); \
  } while(0)

#define PH_OPEN   SB(); __builtin_amdgcn_s_barrier(); LGKM0; SB(); __builtin_amdgcn_s_setprio(1)
#define PH_CLOSE  __builtin_amdgcn_s_setprio(0); SB()
#define PH_END    __builtin_amdgcn_s_barrier(); SB()

template<int MODE>
__global__ __launch_bounds__(512,2) void k_gemm8(const unsigned short* __restrict__ A,
                       const unsigned short* __restrict__ Bm,
                       const float* __restrict__ bias0, const float* __restrict__ bias1,
                       const float* __restrict__ bias2,
                       unsigned short* __restrict__ q_ws, unsigned short* __restrict__ k_ws,
                       unsigned short* __restrict__ v_ws, float* __restrict__ outf)
{
  __shared__ char smem[131072];   // A: buf*32768+hf*16384 @0 ; B same @65536 ; XOR-swizzled
  const int tid = threadIdx.x, lane = tid&63, wid = tid>>6;
  const int g = lane>>4, l15 = lane&15;
  const int wr = wid>>2, wc = wid&3;      // 2M x 4N wave grid; wave tile 128x64

  constexpr int NN = (MODE==0)? 12 : 4;
  const int x  = blockIdx.x & 7;
  const int c  = blockIdx.x >> 3;
  const int m0 = ((c/NN)*8 + x) << 8;
  const int n0 = (c%NN) << 8;

  f32x4 acc[8][4];
  #pragma unroll
  for (int i=0;i<8;i++)
    #pragma unroll
    for (int j=0;j<4;j++) acc[i][j] = f32x4{0.f,0.f,0.f,0.f};

  const int sw = (l15&7)<<4;
  const int brow = (wc&1)*64;

  // ---- loop-invariant LDS read bases (per-lane), reads = base + imm ----
  const char* dsA00 = smem + wr*16384 + l15*128 + ((g*16) ^ sw);          // buf0 ks0
  const char* dsA01 = smem + wr*16384 + l15*128 + ((64+g*16) ^ sw);      // buf0 ks1
  const char* dsA10 = dsA00 + 32768;                                     // buf1 ks0
  const char* dsA11 = dsA01 + 32768;
  const char* dsB00 = smem + 65536 + (wc>>1)*16384 + (brow+l15)*128 + ((g*16) ^ sw);
  const char* dsB01 = smem + 65536 + (wc>>1)*16384 + (brow+l15)*128 + ((64+g*16) ^ sw);
  const char* dsB10 = dsB00 + 32768;
  const char* dsB11 = dsB01 + 32768;

  // ---- loop-invariant global stage ptrs (per-lane); advance +256B/iter ----
  const int rj = tid>>3;                                  // lane row (j=0); j=1 adds 64 rows
  const int cs = ((tid*16)&127) ^ ((rj&7)<<4);            // pre-swizzled source col
  const char* pgA0_0 = (const char*)A  + (size_t)(m0 +       rj)*2048 + cs;
  const char* pgA0_1 = (const char*)A  + (size_t)(m0 +  64 + rj)*2048 + cs;
  const char* pgA1_0 = (const char*)A  + (size_t)(m0 + 128 + rj)*2048 + cs;
  const char* pgA1_1 = (const char*)A  + (size_t)(m0 + 192 + rj)*2048 + cs;
  const char* pgB0_0 = (const char*)Bm + (size_t)(n0 +       rj)*2048 + cs;
  const char* pgB0_1 = (const char*)Bm + (size_t)(n0 +  64 + rj)*2048 + cs;
  const char* pgB1_0 = (const char*)Bm + (size_t)(n0 + 128 + rj)*2048 + cs;
  const char* pgB1_1 = (const char*)Bm + (size_t)(n0 + 192 + rj)*2048 + cs;

  bf16x8 aF[4], bF[4];

  // prologue: A(0) both halves, B(0) both halves, B0(1); vmcnt(2) leaves B0(1) in flight
  STG2(pgA0_0, pgA0_1, 0, 1, 0, 0);
  STG2(pgA1_0, pgA1_1, 0, 1, 0, 1);
  STG2(pgB0_0, pgB0_1, 0, 0, 0, 0);
  STG2(pgB1_0, pgB1_1, 0, 0, 0, 1);
  STG2(pgB0_0, pgB0_1, 128, 0, 1, 0);
  VMC(2);
  __builtin_amdgcn_s_barrier(); SB();

  #pragma unroll 1
  for (int i=0;i<7;++i){
    // ph1: tile T ks0 mf0-3 + B ks0; stage B1(T+1)
    RDA(aF,0,dsA00); RDB(bF,dsB00); STG2(pgB1_0,pgB1_1,128,0,1,1);
    PH_OPEN; QUAD16(aF,bF,0); PH_CLOSE; PH_END;
    // ph2: ks0 mf4-7; stage A0(T+1)
    RDA(aF,4,dsA00); STG2(pgA0_0,pgA0_1,128,1,1,0);
    PH_OPEN; QUAD16(aF,bF,4); PH_CLOSE; PH_END;
    // ph3: ks1 mf0-3 + B ks1; stage A1(T+1)
    RDA(aF,0,dsA01); RDB(bF,dsB01); STG2(pgA1_0,pgA1_1,128,1,1,1);
    PH_OPEN; QUAD16(aF,bF,0); PH_CLOSE; PH_END;
    // ph4: ks1 mf4-7; stage B0(T+2); vmcnt(2) -> tile T+1 landed
    RDA(aF,4,dsA01); STG2(pgB0_0,pgB0_1,256,0,0,0);
    PH_OPEN; QUAD16(aF,bF,4); PH_CLOSE; VMC(2); PH_END;
    // ph5: tile T+1 ks0 mf0-3 + B; stage B1(T+2)
    RDA(aF,0,dsA10); RDB(bF,dsB10); STG2(pgB1_0,pgB1_1,256,0,0,1);
    PH_OPEN; QUAD16(aF,bF,0); PH_CLOSE; PH_END;
    // ph6: stage A0(T+2)
    RDA(aF,4,dsA10); STG2(pgA0_0,pgA0_1,256,1,0,0);
    PH_OPEN; QUAD16(aF,bF,4); PH_CLOSE; PH_END;
    // ph7: stage A1(T+2)
    RDA(aF,0,dsA11); RDB(bF,dsB11); STG2(pgA1_0,pgA1_1,256,1,0,1);
    PH_OPEN; QUAD16(aF,bF,0); PH_CLOSE; PH_END;
    // ph8: stage B0(T+3); vmcnt(2) -> tile T+2 landed
    RDA(aF,4,dsA11); STG2(pgB0_0,pgB0_1,384,0,1,0);
    PH_OPEN; QUAD16(aF,bF,4); PH_CLOSE; VMC(2); PH_END;
    pgA0_0 += 256; pgA0_1 += 256; pgA1_0 += 256; pgA1_1 += 256;
    pgB0_0 += 256; pgB0_1 += 256; pgB1_0 += 256; pgB1_1 += 256;
  }
  {
    // tail: tiles 14,15 — finish staging tile15 (B1,A0,A1), no further prefetch
    RDA(aF,0,dsA00); RDB(bF,dsB00); STG2(pgB1_0,pgB1_1,128,0,1,1);
    PH_OPEN; QUAD16(aF,bF,0); PH_CLOSE; PH_END;
    RDA(aF,4,dsA00); STG2(pgA0_0,pgA0_1,128,1,1,0);
    PH_OPEN; QUAD16(aF,bF,4); PH_CLOSE; PH_END;
    RDA(aF,0,dsA01); RDB(bF,dsB01); STG2(pgA1_0,pgA1_1,128,1,1,1);
    PH_OPEN; QUAD16(aF,bF,0); PH_CLOSE; PH_END;
    RDA(aF,4,dsA01);
    PH_OPEN; QUAD16(aF,bF,4); PH_CLOSE; VMC(0); PH_END;
    RDA(aF,0,dsA10); RDB(bF,dsB10);
    PH_OPEN; QUAD16(aF,bF,0); PH_CLOSE; PH_END;
    RDA(aF,4,dsA10);
    PH_OPEN; QUAD16(aF,bF,4); PH_CLOSE; PH_END;
    RDA(aF,0,dsA11); RDB(bF,dsB11);
    PH_OPEN; QUAD16(aF,bF,0); PH_CLOSE; PH_END;
    RDA(aF,4,dsA11);
    PH_OPEN; QUAD16(aF,bF,4); PH_CLOSE; PH_END;
  }

  // ---------------- epilogue ----------------
  if constexpr (MODE==0){
    const int z  = n0>>10;
    const int nE = n0 & 1023;
    const float* bias = (z==0)? bias0 : (z==1)? bias1 : bias2;
    #pragma unroll
    for (int nf=0;nf<4;nf++){
      const int ncol = nE + wc*64 + nf*16 + l15;
      const float bn = bias[ncol];
      const int h = ncol>>6, d = ncol&63;
      #pragma unroll
      for (int mf=0;mf<8;mf++){
        const int mb = m0 + wr*128 + mf*16 + g*4;
        if (z==2){
          const int b = mb>>12, s = mb&4095, nw = s>>8, w0 = s&255;
          unsigned short pk0=f2bf(acc[mf][nf][0]+bn), pk1=f2bf(acc[mf][nf][1]+bn),
                         pk2=f2bf(acc[mf][nf][2]+bn), pk3=f2bf(acc[mf][nf][3]+bn);
          size_t idx = ((((size_t)(b*16+h)*16 + nw)*64 + d)<<8) + w0;
          *(ushort4*)(v_ws + idx) = make_ushort4(pk0,pk1,pk2,pk3);
        } else {
          unsigned short* dst = (z==0)? q_ws : k_ws;
          const float scale = (z==0)? 0.125f : 1.0f;
          #pragma unroll
          for (int r=0;r<4;r++){
            const int m = mb + r, b = m>>12, s = m&4095;
            dst[(((size_t)(b*16+h)*4096 + s)<<6) + d] = f2bf((acc[mf][nf][r]+bn)*scale);
          }
        }
      }
    }
  } else {
    #pragma unroll
    for (int nf=0;nf<4;nf++){
      const int n = n0 + wc*64 + nf*16 + l15;
      const float bn = bias0[n];
      #pragma unroll
      for (int mf=0;mf<8;mf++)
        #pragma unroll
        for (int r=0;r<4;r++){
          const int m = m0 + wr*128 + mf*16 + g*4 + r;
          outf[(size_t)m*1024 + n] = acc[mf][nf][r] + bn;
        }
    }
  }
}

// ---------------- windowed attention: 1 block per (b,h,window), 4 waves x 64 q-rows ----------------
__global__ __launch_bounds__(256,2) void k_attn(const unsigned short* __restrict__ qw,
                                                const unsigned short* __restrict__ kw,
                                                const unsigned short* __restrict__ vw,
                                                unsigned short* __restrict__ ow)
{
  __shared__ unsigned short Ks[2][4096];
  __shared__ unsigned short Vs[2][4096];
  __shared__ unsigned short Ps[4][4096];
  const int tid = threadIdx.x, lane = tid&63, wid = tid>>6;
  const int g = lane>>4, l15 = lane&15;
  const int bhn = blockIdx.x;
  const int nw = bhn&15, h = (bhn>>4)&15, b = bhn>>8;

  const size_t qkbase = ((size_t)((b*16+h)*4096 + nw*256))<<6;
  const unsigned short* Qg = qw + qkbase;
  const unsigned short* Kg = kw + qkbase;
  const unsigned short* Vg = vw + (((size_t)(b*16+h)*16 + nw)<<14);
  const float NEG_INF = -__builtin_inff();

  bf16x8 qa[4][2];
  #pragma unroll
  for (int qf=0;qf<4;qf++)
    #pragma unroll
    for (int ks=0;ks<2;ks++)
      qa[qf][ks] = *(const bf16x8*)((const char*)Qg + (wid*64 + qf*16 + l15)*128 + ks*64 + g*16);

  auto stage = [&](int kt, int bi){
    #pragma unroll
    for (int i=0;i<4;i++){
      const int chunk = wid*4 + i;
      const int obase = (chunk&7)<<10;
      const int o = obase + lane*16;
      const int r = o>>7, cb = o&127;
      const int cs = cb ^ ((r&7)<<4);
      if (chunk < 8)
        gload_lds16((const char*)Kg + (kt*64 + r)*128 + cs, (char*)Ks[bi] + obase);
      else
        gload_lds16((const char*)Vg + r*512 + kt*128 + cs, (char*)Vs[bi] + obase);
    }
  };

  f32x4 oacc[4][4];
  float mrow[4][4], lrow[4][4];
  #pragma unroll
  for (int i=0;i<4;i++)
    #pragma unroll
    for (int j=0;j<4;j++){ oacc[i][j] = f32x4{0.f,0.f,0.f,0.f}; mrow[i][j] = NEG_INF; lrow[i][j] = 0.f; }

  stage(0,0);
  __syncthreads();
  for (int kt=0;kt<4;kt++){
    const int cur = kt&1;
    if (kt<3) stage(kt+1, cur^1);

    bf16x8 kb[4][2];
    #pragma unroll
    for (int kf=0;kf<4;kf++)
      #pragma unroll
      for (int ks=0;ks<2;ks++){
        const int kr = kf*16 + l15, cb = ks*64 + g*16;
        kb[kf][ks] = *(const bf16x8*)((const char*)Ks[cur] + kr*128 + (cb ^ ((kr&7)<<4)));
      }

    unsigned short* P = Ps[wid];
    #pragma unroll
    for (int qf=0;qf<4;qf++){
      f32x4 sfr[4];
      #pragma unroll
      for (int kf=0;kf<4;kf++){
        f32x4 zz = f32x4{0.f,0.f,0.f,0.f};
        zz = MFMA(qa[qf][0], kb[kf][0], zz);
        sfr[kf] = MFMA(qa[qf][1], kb[kf][1], zz);
      }
      #pragma unroll
      for (int r=0;r<4;r++){
        float t = fmaxf(fmaxf(sfr[0][r],sfr[1][r]), fmaxf(sfr[2][r],sfr[3][r]));
        t = fmaxf(t, __shfl_xor(t,1,64)); t = fmaxf(t, __shfl_xor(t,2,64));
        t = fmaxf(t, __shfl_xor(t,4,64)); t = fmaxf(t, __shfl_xor(t,8,64));
        const float mo = mrow[qf][r];
        const float mn = fmaxf(mo, t);
        const float alpha = __expf(mo - mn);
        float rs = 0.f;
        #pragma unroll
        for (int kf=0;kf<4;kf++){ float p = __expf(sfr[kf][r]-mn); sfr[kf][r] = p; rs += p; }
        rs += __shfl_xor(rs,1,64); rs += __shfl_xor(rs,2,64);
        rs += __shfl_xor(rs,4,64); rs += __shfl_xor(rs,8,64);
        lrow[qf][r] = lrow[qf][r]*alpha + rs;
        mrow[qf][r] = mn;
        #pragma unroll
        for (int df=0;df<4;df++) oacc[qf][df][r] *= alpha;
        const int prow = qf*16 + g*4 + r;
        const int sw = (prow&7)<<4;
        char* Pb = (char*)P + prow*128;
        #pragma unroll
        for (int kf=0;kf<4;kf++)
          *(unsigned short*)(Pb + (((kf*16 + l15)*2) ^ sw)) = f2bf(sfr[kf][r]);
      }
    }
    __builtin_amdgcn_sched_barrier(0);

    bf16x8 vb[4][2];
    #pragma unroll
    for (int df=0;df<4;df++)
      #pragma unroll
      for (int ks=0;ks<2;ks++){
        const int d = df*16 + l15, cb = ks*64 + g*16;
        vb[df][ks] = *(const bf16x8*)((const char*)Vs[cur] + d*128 + (cb ^ ((d&7)<<4)));
      }
    #pragma unroll
    for (int qf=0;qf<4;qf++){
      const int pr = qf*16 + l15;
      const bf16x8 pa0 = *(const bf16x8*)((const char*)P + pr*128 + ((g*16)      ^ ((pr&7)<<4)));
      const bf16x8 pa1 = *(const bf16x8*)((const char*)P + pr*128 + ((64 + g*16) ^ ((pr&7)<<4)));
      #pragma unroll
      for (int df=0;df<4;df++){
        oacc[qf][df] = MFMA(pa0, vb[df][0], oacc[qf][df]);
        oacc[qf][df] = MFMA(pa1, vb[df][1], oacc[qf][df]);
      }
    }
    __syncthreads();
  }

  #pragma unroll
  for (int qf=0;qf<4;qf++)
    #pragma unroll
    for (int r=0;r<4;r++){
      const float inv = 1.f / lrow[qf][r];
      const int srow = nw*256 + wid*64 + qf*16 + g*4 + r;
      const size_t base = ((size_t)b*4096 + srow)*1024 + (size_t)h*64;
      #pragma unroll
      for (int df=0;df<4;df++)
        ow[base + df*16 + l15] = f2bf(oacc[qf][df][r]*inv);
    }
}

// ---------------- launch ----------------
extern "C" void kernel_launch(void* const* d_in, const int* in_sizes, int n_in,
                              void* d_out, int out_size, void* d_ws, size_t ws_size,
                              hipStream_t stream)
{
  const float* x  = (const float*)d_in[0];
  const float* Wq = (const float*)d_in[1];
  const float* bq = (const float*)d_in[2];
  const float* Wk = (const float*)d_in[3];
  const float* bk = (const float*)d_in[4];
  const float* Wv = (const float*)d_in[5];
  const float* bv = (const float*)d_in[6];
  const float* Wo = (const float*)d_in[7];
  const float* bo = (const float*)d_in[8];
  float* out = (float*)d_out;

  char* ws = (char*)d_ws;
  unsigned short* xbf  = (unsigned short*)(ws);
  unsigned short* wT   = (unsigned short*)(ws + (size_t)32*1048576);
  unsigned short* q_ws = (unsigned short*)(ws + (size_t)40*1048576);
  unsigned short* k_ws = (unsigned short*)(ws + (size_t)72*1048576);
  unsigned short* v_ws = (unsigned short*)(ws + (size_t)104*1048576);
  unsigned short* obf  = xbf;

  k_cvt_x<<<4096,256,0,stream>>>(x, xbf);
  k_cvt_wT<<<dim3(32,32,4),256,0,stream>>>(Wq,Wk,Wv,Wo, wT);
  k_gemm8<0><<<768,512,0,stream>>>(xbf, wT, bq,bk,bv, q_ws,k_ws,v_ws, nullptr);
  k_attn<<<1024,256,0,stream>>>(q_ws,k_ws,v_ws, obf);
  k_gemm8<1><<<256,512,0,stream>>>(obf, wT + (size_t)3*1048576, bo,nullptr,nullptr,
                                   nullptr,nullptr,nullptr, out);
}

// Round 9
// 255.384 us; speedup vs baseline: 2.1472x; 1.0034x over previous
//
#include <hip/hip_runtime.h>

typedef __bf16 bf16x8 __attribute__((ext_vector_type(8)));
typedef float  f32x4  __attribute__((ext_vector_type(4)));

#define MFMA(a,b,c) __builtin_amdgcn_mfma_f32_16x16x32_bf16((a),(b),(c),0,0,0)
#define VMC(N) asm volatile("s_waitcnt vmcnt(" #N ")" ::: "memory")

__device__ __forceinline__ unsigned short f2bf(float f){
  unsigned u = __builtin_bit_cast(unsigned, f);
  u += 0x7fffu + ((u>>16)&1u);
  return (unsigned short)(u>>16);
}
__device__ __forceinline__ unsigned pack_bf2(float a, float b){
  return (unsigned)f2bf(a) | ((unsigned)f2bf(b)<<16);
}
__device__ __forceinline__ void gload_lds16(const void* g, void* l){
  __builtin_amdgcn_global_load_lds((__attribute__((address_space(1))) void*)(g),
                                   (__attribute__((address_space(3))) void*)(l), 16, 0, 0);
}

// ---------------- convert x (fp32 -> bf16) ----------------
__global__ void k_cvt_x(const float* __restrict__ x, unsigned short* __restrict__ o){
  const size_t t = (size_t)blockIdx.x*256 + threadIdx.x;
  #pragma unroll
  for (int i=0;i<4;i++){
    size_t idx = t + (size_t)i*1048576;
    float4 f = ((const float4*)x)[idx];
    ((uint2*)o)[idx] = make_uint2(pack_bf2(f.x,f.y), pack_bf2(f.z,f.w));
  }
}

// ---------------- convert + transpose weights: W[K][N] fp32 -> WT[N][K] bf16 ----------------
__global__ void k_cvt_wT(const float* __restrict__ Wq, const float* __restrict__ Wk,
                         const float* __restrict__ Wv, const float* __restrict__ Wo,
                         unsigned short* __restrict__ wT){
  const int z = blockIdx.z;
  const float* W = (z==0)?Wq:(z==1)?Wk:(z==2)?Wv:Wo;
  unsigned short* out = wT + (size_t)z*1048576;
  __shared__ float tile[32][33];
  const int r0 = blockIdx.y*32, c0 = blockIdx.x*32;
  const int r = threadIdx.x>>5, c = threadIdx.x&31;
  #pragma unroll
  for (int i=0;i<4;i++) tile[r + i*8][c] = W[(size_t)(r0 + r + i*8)*1024 + c0 + c];
  __syncthreads();
  #pragma unroll
  for (int i=0;i<4;i++)
    out[(size_t)(c0 + r + i*8)*1024 + r0 + c] = f2bf(tile[c][r + i*8]);
}

// ---------------- 256^2 8-wave 8-phase GEMM — UNPINNED (no sched_barrier / no lgkmcnt(0)) ----------------
// Slots/barriers/vmcnt identical to r8. Compiler free to stage lgkmcnt(N) and interleave
// reads/MFMA/stage inside each phase (m141 lesson: order-pinning defeats the scheduler).
#define QUAD16(AF, BF, MF0) do { \
  _Pragma("unroll") \
  for (int mf_=0; mf_<4; ++mf_){ \
    _Pragma("unroll") \
    for (int nf_=0; nf_<4; ++nf_) \
      acc[MF0+mf_][nf_] = MFMA(AF[mf_], BF[nf_], acc[MF0+mf_][nf_]); \
  } } while(0)

#define RDA(DST, MF0, P) do { \
  _Pragma("unroll") \
  for (int mf_=0; mf_<4; ++mf_) \
    DST[mf_] = *(const bf16x8*)((P) + ((MF0)+mf_)*2048); \
  } while(0)

#define RDB(DST, P) do { \
  _Pragma("unroll") \
  for (int nf_=0; nf_<4; ++nf_) \
    DST[nf_] = *(const bf16x8*)((P) + nf_*2048); \
  } while(0)

#define STG2(P0, P1, DT, ISA, BUF, HF) do { \
  char* _ld = smem + ((ISA)?0:65536) + (BUF)*32768 + (HF)*16384 + wid*1024; \
  gload_lds16((P0) + (DT), _ld); \
  gload_lds16((P1) + (DT), _ld + 8192); \
  } while(0)

#define PH_OPEN   __builtin_amdgcn_s_barrier(); __builtin_amdgcn_s_setprio(1)
#define PH_CLOSE  __builtin_amdgcn_s_setprio(0)
#define PH_END    __builtin_amdgcn_s_barrier()

template<int MODE>
__global__ __launch_bounds__(512,2) void k_gemm8(const unsigned short* __restrict__ A,
                       const unsigned short* __restrict__ Bm,
                       const float* __restrict__ bias0, const float* __restrict__ bias1,
                       const float* __restrict__ bias2,
                       unsigned short* __restrict__ q_ws, unsigned short* __restrict__ k_ws,
                       unsigned short* __restrict__ v_ws, float* __restrict__ outf)
{
  __shared__ char smem[131072];   // A: buf*32768+hf*16384 @0 ; B same @65536 ; XOR-swizzled
  const int tid = threadIdx.x, lane = tid&63, wid = tid>>6;
  const int g = lane>>4, l15 = lane&15;
  const int wr = wid>>2, wc = wid&3;      // 2M x 4N wave grid; wave tile 128x64

  constexpr int NN = (MODE==0)? 12 : 4;
  const int x  = blockIdx.x & 7;
  const int c  = blockIdx.x >> 3;
  const int m0 = ((c/NN)*8 + x) << 8;
  const int n0 = (c%NN) << 8;

  f32x4 acc[8][4];
  #pragma unroll
  for (int i=0;i<8;i++)
    #pragma unroll
    for (int j=0;j<4;j++) acc[i][j] = f32x4{0.f,0.f,0.f,0.f};

  const int sw = (l15&7)<<4;
  const int brow = (wc&1)*64;

  // ---- loop-invariant LDS read bases (per-lane), reads = base + imm ----
  const char* dsA00 = smem + wr*16384 + l15*128 + ((g*16) ^ sw);          // buf0 ks0
  const char* dsA01 = smem + wr*16384 + l15*128 + ((64+g*16) ^ sw);      // buf0 ks1
  const char* dsA10 = dsA00 + 32768;                                     // buf1 ks0
  const char* dsA11 = dsA01 + 32768;
  const char* dsB00 = smem + 65536 + (wc>>1)*16384 + (brow+l15)*128 + ((g*16) ^ sw);
  const char* dsB01 = smem + 65536 + (wc>>1)*16384 + (brow+l15)*128 + ((64+g*16) ^ sw);
  const char* dsB10 = dsB00 + 32768;
  const char* dsB11 = dsB01 + 32768;

  // ---- loop-invariant global stage ptrs (per-lane); advance +256B/iter ----
  const int rj = tid>>3;
  const int cs = ((tid*16)&127) ^ ((rj&7)<<4);
  const char* pgA0_0 = (const char*)A  + (size_t)(m0 +       rj)*2048 + cs;
  const char* pgA0_1 = (const char*)A  + (size_t)(m0 +  64 + rj)*2048 + cs;
  const char* pgA1_0 = (const char*)A  + (size_t)(m0 + 128 + rj)*2048 + cs;
  const char* pgA1_1 = (const char*)A  + (size_t)(m0 + 192 + rj)*2048 + cs;
  const char* pgB0_0 = (const char*)Bm + (size_t)(n0 +       rj)*2048 + cs;
  const char* pgB0_1 = (const char*)Bm + (size_t)(n0 +  64 + rj)*2048 + cs;
  const char* pgB1_0 = (const char*)Bm + (size_t)(n0 + 128 + rj)*2048 + cs;
  const char* pgB1_1 = (const char*)Bm + (size_t)(n0 + 192 + rj)*2048 + cs;

  bf16x8 aF[4], bF[4];

  // prologue: A(0) both halves, B(0) both halves, B0(1); vmcnt(2) leaves B0(1) in flight
  STG2(pgA0_0, pgA0_1, 0, 1, 0, 0);
  STG2(pgA1_0, pgA1_1, 0, 1, 0, 1);
  STG2(pgB0_0, pgB0_1, 0, 0, 0, 0);
  STG2(pgB1_0, pgB1_1, 0, 0, 0, 1);
  STG2(pgB0_0, pgB0_1, 128, 0, 1, 0);
  VMC(2);
  __builtin_amdgcn_s_barrier();

  #pragma unroll 1
  for (int i=0;i<7;++i){
    // ph1: tile T ks0 mf0-3 + B ks0; stage B1(T+1)
    RDA(aF,0,dsA00); RDB(bF,dsB00); STG2(pgB1_0,pgB1_1,128,0,1,1);
    PH_OPEN; QUAD16(aF,bF,0); PH_CLOSE; PH_END;
    // ph2: ks0 mf4-7; stage A0(T+1)
    RDA(aF,4,dsA00); STG2(pgA0_0,pgA0_1,128,1,1,0);
    PH_OPEN; QUAD16(aF,bF,4); PH_CLOSE; PH_END;
    // ph3: ks1 mf0-3 + B ks1; stage A1(T+1)
    RDA(aF,0,dsA01); RDB(bF,dsB01); STG2(pgA1_0,pgA1_1,128,1,1,1);
    PH_OPEN; QUAD16(aF,bF,0); PH_CLOSE; PH_END;
    // ph4: ks1 mf4-7; stage B0(T+2); vmcnt(2) -> tile T+1 landed
    RDA(aF,4,dsA01); STG2(pgB0_0,pgB0_1,256,0,0,0);
    PH_OPEN; QUAD16(aF,bF,4); PH_CLOSE; VMC(2); PH_END;
    // ph5: tile T+1 ks0 mf0-3 + B; stage B1(T+2)
    RDA(aF,0,dsA10); RDB(bF,dsB10); STG2(pgB1_0,pgB1_1,256,0,0,1);
    PH_OPEN; QUAD16(aF,bF,0); PH_CLOSE; PH_END;
    // ph6: stage A0(T+2)
    RDA(aF,4,dsA10); STG2(pgA0_0,pgA0_1,256,1,0,0);
    PH_OPEN; QUAD16(aF,bF,4); PH_CLOSE; PH_END;
    // ph7: stage A1(T+2)
    RDA(aF,0,dsA11); RDB(bF,dsB11); STG2(pgA1_0,pgA1_1,256,1,0,1);
    PH_OPEN; QUAD16(aF,bF,0); PH_CLOSE; PH_END;
    // ph8: stage B0(T+3); vmcnt(2) -> tile T+2 landed
    RDA(aF,4,dsA11); STG2(pgB0_0,pgB0_1,384,0,1,0);
    PH_OPEN; QUAD16(aF,bF,4); PH_CLOSE; VMC(2); PH_END;
    pgA0_0 += 256; pgA0_1 += 256; pgA1_0 += 256; pgA1_1 += 256;
    pgB0_0 += 256; pgB0_1 += 256; pgB1_0 += 256; pgB1_1 += 256;
  }
  {
    // tail: tiles 14,15 — finish staging tile15 (B1,A0,A1), no further prefetch
    RDA(aF,0,dsA00); RDB(bF,dsB00); STG2(pgB1_0,pgB1_1,128,0,1,1);
    PH_OPEN; QUAD16(aF,bF,0); PH_CLOSE; PH_END;
    RDA(aF,4,dsA00); STG2(pgA0_0,pgA0_1,128,1,1,0);
    PH_OPEN; QUAD16(aF,bF,4); PH_CLOSE; PH_END;
    RDA(aF,0,dsA01); RDB(bF,dsB01); STG2(pgA1_0,pgA1_1,128,1,1,1);
    PH_OPEN; QUAD16(aF,bF,0); PH_CLOSE; PH_END;
    RDA(aF,4,dsA01);
    PH_OPEN; QUAD16(aF,bF,4); PH_CLOSE; VMC(0); PH_END;
    RDA(aF,0,dsA10); RDB(bF,dsB10);
    PH_OPEN; QUAD16(aF,bF,0); PH_CLOSE; PH_END;
    RDA(aF,4,dsA10);
    PH_OPEN; QUAD16(aF,bF,4); PH_CLOSE; PH_END;
    RDA(aF,0,dsA11); RDB(bF,dsB11);
    PH_OPEN; QUAD16(aF,bF,0); PH_CLOSE; PH_END;
    RDA(aF,4,dsA11);
    PH_OPEN; QUAD16(aF,bF,4); PH_CLOSE; PH_END;
  }

  // ---------------- epilogue ----------------
  if constexpr (MODE==0){
    const int z  = n0>>10;
    const int nE = n0 & 1023;
    const float* bias = (z==0)? bias0 : (z==1)? bias1 : bias2;
    #pragma unroll
    for (int nf=0;nf<4;nf++){
      const int ncol = nE + wc*64 + nf*16 + l15;
      const float bn = bias[ncol];
      const int h = ncol>>6, d = ncol&63;
      #pragma unroll
      for (int mf=0;mf<8;mf++){
        const int mb = m0 + wr*128 + mf*16 + g*4;
        if (z==2){
          const int b = mb>>12, s = mb&4095, nw = s>>8, w0 = s&255;
          unsigned short pk0=f2bf(acc[mf][nf][0]+bn), pk1=f2bf(acc[mf][nf][1]+bn),
                         pk2=f2bf(acc[mf][nf][2]+bn), pk3=f2bf(acc[mf][nf][3]+bn);
          size_t idx = ((((size_t)(b*16+h)*16 + nw)*64 + d)<<8) + w0;
          *(ushort4*)(v_ws + idx) = make_ushort4(pk0,pk1,pk2,pk3);
        } else {
          unsigned short* dst = (z==0)? q_ws : k_ws;
          const float scale = (z==0)? 0.125f : 1.0f;
          #pragma unroll
          for (int r=0;r<4;r++){
            const int m = mb + r, b = m>>12, s = m&4095;
            dst[(((size_t)(b*16+h)*4096 + s)<<6) + d] = f2bf((acc[mf][nf][r]+bn)*scale);
          }
        }
      }
    }
  } else {
    #pragma unroll
    for (int nf=0;nf<4;nf++){
      const int n = n0 + wc*64 + nf*16 + l15;
      const float bn = bias0[n];
      #pragma unroll
      for (int mf=0;mf<8;mf++)
        #pragma unroll
        for (int r=0;r<4;r++){
          const int m = m0 + wr*128 + mf*16 + g*4 + r;
          outf[(size_t)m*1024 + n] = acc[mf][nf][r] + bn;
        }
    }
  }
}

// ---------------- windowed attention: 1 block per (b,h,window), 4 waves x 64 q-rows ----------------
__global__ __launch_bounds__(256,2) void k_attn(const unsigned short* __restrict__ qw,
                                                const unsigned short* __restrict__ kw,
                                                const unsigned short* __restrict__ vw,
                                                unsigned short* __restrict__ ow)
{
  __shared__ unsigned short Ks[2][4096];
  __shared__ unsigned short Vs[2][4096];
  __shared__ unsigned short Ps[4][4096];
  const int tid = threadIdx.x, lane = tid&63, wid = tid>>6;
  const int g = lane>>4, l15 = lane&15;
  const int bhn = blockIdx.x;
  const int nw = bhn&15, h = (bhn>>4)&15, b = bhn>>8;

  const size_t qkbase = ((size_t)((b*16+h)*4096 + nw*256))<<6;
  const unsigned short* Qg = qw + qkbase;
  const unsigned short* Kg = kw + qkbase;
  const unsigned short* Vg = vw + (((size_t)(b*16+h)*16 + nw)<<14);
  const float NEG_INF = -__builtin_inff();

  bf16x8 qa[4][2];
  #pragma unroll
  for (int qf=0;qf<4;qf++)
    #pragma unroll
    for (int ks=0;ks<2;ks++)
      qa[qf][ks] = *(const bf16x8*)((const char*)Qg + (wid*64 + qf*16 + l15)*128 + ks*64 + g*16);

  auto stage = [&](int kt, int bi){
    #pragma unroll
    for (int i=0;i<4;i++){
      const int chunk = wid*4 + i;
      const int obase = (chunk&7)<<10;
      const int o = obase + lane*16;
      const int r = o>>7, cb = o&127;
      const int cs = cb ^ ((r&7)<<4);
      if (chunk < 8)
        gload_lds16((const char*)Kg + (kt*64 + r)*128 + cs, (char*)Ks[bi] + obase);
      else
        gload_lds16((const char*)Vg + r*512 + kt*128 + cs, (char*)Vs[bi] + obase);
    }
  };

  f32x4 oacc[4][4];
  float mrow[4][4], lrow[4][4];
  #pragma unroll
  for (int i=0;i<4;i++)
    #pragma unroll
    for (int j=0;j<4;j++){ oacc[i][j] = f32x4{0.f,0.f,0.f,0.f}; mrow[i][j] = NEG_INF; lrow[i][j] = 0.f; }

  stage(0,0);
  __syncthreads();
  for (int kt=0;kt<4;kt++){
    const int cur = kt&1;
    if (kt<3) stage(kt+1, cur^1);

    bf16x8 kb[4][2];
    #pragma unroll
    for (int kf=0;kf<4;kf++)
      #pragma unroll
      for (int ks=0;ks<2;ks++){
        const int kr = kf*16 + l15, cb = ks*64 + g*16;
        kb[kf][ks] = *(const bf16x8*)((const char*)Ks[cur] + kr*128 + (cb ^ ((kr&7)<<4)));
      }

    unsigned short* P = Ps[wid];
    #pragma unroll
    for (int qf=0;qf<4;qf++){
      f32x4 sfr[4];
      #pragma unroll
      for (int kf=0;kf<4;kf++){
        f32x4 zz = f32x4{0.f,0.f,0.f,0.f};
        zz = MFMA(qa[qf][0], kb[kf][0], zz);
        sfr[kf] = MFMA(qa[qf][1], kb[kf][1], zz);
      }
      #pragma unroll
      for (int r=0;r<4;r++){
        float t = fmaxf(fmaxf(sfr[0][r],sfr[1][r]), fmaxf(sfr[2][r],sfr[3][r]));
        t = fmaxf(t, __shfl_xor(t,1,64)); t = fmaxf(t, __shfl_xor(t,2,64));
        t = fmaxf(t, __shfl_xor(t,4,64)); t = fmaxf(t, __shfl_xor(t,8,64));
        const float mo = mrow[qf][r];
        const float mn = fmaxf(mo, t);
        const float alpha = __expf(mo - mn);
        float rs = 0.f;
        #pragma unroll
        for (int kf=0;kf<4;kf++){ float p = __expf(sfr[kf][r]-mn); sfr[kf][r] = p; rs += p; }
        rs += __shfl_xor(rs,1,64); rs += __shfl_xor(rs,2,64);
        rs += __shfl_xor(rs,4,64); rs += __shfl_xor(rs,8,64);
        lrow[qf][r] = lrow[qf][r]*alpha + rs;
        mrow[qf][r] = mn;
        #pragma unroll
        for (int df=0;df<4;df++) oacc[qf][df][r] *= alpha;
        const int prow = qf*16 + g*4 + r;
        const int sw = (prow&7)<<4;
        char* Pb = (char*)P + prow*128;
        #pragma unroll
        for (int kf=0;kf<4;kf++)
          *(unsigned short*)(Pb + (((kf*16 + l15)*2) ^ sw)) = f2bf(sfr[kf][r]);
      }
    }
    __builtin_amdgcn_sched_barrier(0);

    bf16x8 vb[4][2];
    #pragma unroll
    for (int df=0;df<4;df++)
      #pragma unroll
      for (int ks=0;ks<2;ks++){
        const int d = df*16 + l15, cb = ks*64 + g*16;
        vb[df][ks] = *(const bf16x8*)((const char*)Vs[cur] + d*128 + (cb ^ ((d&7)<<4)));
      }
    #pragma unroll
    for (int qf=0;qf<4;qf++){
      const int pr = qf*16 + l15;
      const bf16x8 pa0 = *(const bf16x8*)((const char*)P + pr*128 + ((g*16)      ^ ((pr&7)<<4)));
      const bf16x8 pa1 = *(const bf16x8*)((const char*)P + pr*128 + ((64 + g*16) ^ ((pr&7)<<4)));
      #pragma unroll
      for (int df=0;df<4;df++){
        oacc[qf][df] = MFMA(pa0, vb[df][0], oacc[qf][df]);
        oacc[qf][df] = MFMA(pa1, vb[df][1], oacc[qf][df]);
      }
    }
    __syncthreads();
  }

  #pragma unroll
  for (int qf=0;qf<4;qf++)
    #pragma unroll
    for (int r=0;r<4;r++){
      const float inv = 1.f / lrow[qf][r];
      const int srow = nw*256 + wid*64 + qf*16 + g*4 + r;
      const size_t base = ((size_t)b*4096 + srow)*1024 + (size_t)h*64;
      #pragma unroll
      for (int df=0;df<4;df++)
        ow[base + df*16 + l15] = f2bf(oacc[qf][df][r]*inv);
    }
}

// ---------------- launch ----------------
extern "C" void kernel_launch(void* const* d_in, const int* in_sizes, int n_in,
                              void* d_out, int out_size, void* d_ws, size_t ws_size,
                              hipStream_t stream)
{
  const float* x  = (const float*)d_in[0];
  const float* Wq = (const float*)d_in[1];
  const float* bq = (const float*)d_in[2];
  const float* Wk = (const float*)d_in[3];
  const float* bk = (const float*)d_in[4];
  const float* Wv = (const float*)d_in[5];
  const float* bv = (const float*)d_in[6];
  const float* Wo = (const float*)d_in[7];
  const float* bo = (const float*)d_in[8];
  float* out = (float*)d_out;

  char* ws = (char*)d_ws;
  unsigned short* xbf  = (unsigned short*)(ws);
  unsigned short* wT   = (unsigned short*)(ws + (size_t)32*1048576);
  unsigned short* q_ws = (unsigned short*)(ws + (size_t)40*1048576);
  unsigned short* k_ws = (unsigned short*)(ws + (size_t)72*1048576);
  unsigned short* v_ws = (unsigned short*)(ws + (size_t)104*1048576);
  unsigned short* obf  = xbf;

  k_cvt_x<<<4096,256,0,stream>>>(x, xbf);
  k_cvt_wT<<<dim3(32,32,4),256,0,stream>>>(Wq,Wk,Wv,Wo, wT);
  k_gemm8<0><<<768,512,0,stream>>>(xbf, wT, bq,bk,bv, q_ws,k_ws,v_ws, nullptr);
  k_attn<<<1024,256,0,stream>>>(q_ws,k_ws,v_ws, obf);
  k_gemm8<1><<<256,512,0,stream>>>(obf, wT + (size_t)3*1048576, bo,nullptr,nullptr,
                                   nullptr,nullptr,nullptr, out);
}